// Round 5
// baseline (4994.640 us; speedup 1.0000x reference)
//
#include <hip/hip_runtime.h>

#define N_NODES 50000
#define N_EDGES 1600000
#define N_TOTAL (N_EDGES + N_NODES)   // edges + self loops
#define F_IN    32
#define HID     64
#define F_OUT   128
#define G       32                    // dst nodes per bucket
#define NB      1563                  // ceil(N_NODES / G)
#define CAP     1344                  // mean 1056 + 9 sigma
#define OVF_CAP 65536

// workspace layout (unsigned units):
//   bcur  [NB+1]   (bcur[NB] = overflow counter)
//   ovf   [OVF_CAP]        at offset 2048
//   bkt   [NB*CAP]         at offset 2048+OVF_CAP   (~8.7 MB total)
#define OFF_OVF 2048
#define OFF_BKT (2048 + OVF_CAP)

// ---------------------------------------------------------------------------
// Kernel A: Q[n] = b1 + x_n @ W1[0:32,:] into d_out cols 0-63 (cols 64-127
// are fully overwritten by gather - no zeroing needed). Also zero bucket
// cursors (ws is re-poisoned 0xAA before every call).
// ---------------------------------------------------------------------------
__global__ __launch_bounds__(256) void node_pre_kernel(
    const float* __restrict__ x,
    const float* __restrict__ W1, const float* __restrict__ b1,
    float* __restrict__ out, unsigned* __restrict__ bcur)
{
    const int n = blockIdx.x * 256 + threadIdx.x;
    if (n <= NB) bcur[n] = 0u;          // NB cursors + overflow counter
    if (n >= N_NODES) return;

    float acc[HID];
    #pragma unroll
    for (int k = 0; k < HID; ++k) acc[k] = b1[k];

    const float4* x4 = (const float4*)(x + (long long)n * F_IN);
    #pragma unroll 1
    for (int c4 = 0; c4 < F_IN / 4; ++c4) {
        const float4 v = x4[c4];
        const float mv[4] = {v.x, v.y, v.z, v.w};
        #pragma unroll
        for (int q = 0; q < 4; ++q) {
            const float* w = W1 + (c4 * 4 + q) * HID;   // wave-uniform
            #pragma unroll
            for (int k = 0; k < HID; ++k) acc[k] = fmaf(mv[q], w[k], acc[k]);
        }
    }

    float4* o4 = (float4*)(out + (long long)n * F_OUT);
    #pragma unroll
    for (int k4 = 0; k4 < HID / 4; ++k4)
        o4[k4] = make_float4(acc[4*k4], acc[4*k4+1], acc[4*k4+2], acc[4*k4+3]);
}

// ---------------------------------------------------------------------------
// Kernel B: single-pass bucketing by dst (coarse sort). One atomicAdd on a
// 6 KB hot cursor array + one packed-u32 store per edge. Overflow (>= 9
// sigma, ~never) goes to a list fixed up after gather.
// ---------------------------------------------------------------------------
__global__ __launch_bounds__(256) void scatter_kernel(
    const int* __restrict__ ei, unsigned* __restrict__ bcur,
    unsigned* __restrict__ bkt, unsigned* __restrict__ ovf)
{
    const int gid = blockIdx.x * 256 + threadIdx.x;
    if (gid >= N_TOTAL) return;
    int s, d;
    if (gid < N_EDGES) { s = ei[gid]; d = ei[N_EDGES + gid]; }
    else               { s = d = gid - N_EDGES; }        // self loop
    const int b = d >> 5;
    const unsigned p = atomicAdd(&bcur[b], 1u);
    if (p < CAP) {
        bkt[(long long)b * CAP + p] = ((unsigned)(d & 31) << 16) | (unsigned)s;
    } else {
        const unsigned q = atomicAdd(&bcur[NB], 1u);
        if (q < OVF_CAP) ovf[q] = ((unsigned)d << 16) | (unsigned)s;
    }
}

// ---------------------------------------------------------------------------
// Kernel C: one block per bucket. Edge-per-lane MLP with h1 REGISTERIZED
// (layer-2 fully unrolled -> static indexing), h2 transposed through a
// per-wave [64][33] LDS buffer in two 32-channel phases, aggregated into a
// block-owned 8 KB LDS agg array via LDS atomicMax. Final agg rows written
// with plain coalesced stores - no global atomics, no load-test fetches.
// LDS 42 KB -> 3 blocks/CU; VGPR capped by launch_bounds(256,3).
// ---------------------------------------------------------------------------
__global__ __launch_bounds__(256, 3) void gather_kernel(
    const float* __restrict__ qagg,     // d_out: [N,128] cols 0-63 = Q
    const float* __restrict__ pos,
    const unsigned* __restrict__ bcur,
    const unsigned* __restrict__ bkt,
    const float* __restrict__ W1p,      // W1 rows 32..34, [3, 64]
    const float* __restrict__ W2, const float* __restrict__ b2,
    float* __restrict__ out)
{
    __shared__ unsigned aggs[G * HID];      // 8 KB, block-owned agg
    __shared__ float    tbuf[4 * 64 * 33];  // 33 KB, per-wave transpose bufs
    const int t = threadIdx.x, lane = t & 63, w = t >> 6;
    const int b = blockIdx.x;
    const unsigned cnt = min(bcur[b], (unsigned)CAP);
    float* wb = tbuf + w * (64 * 33);

    for (int i = t; i < G * HID; i += 256) aggs[i] = 0u;
    __syncthreads();

    const long long base = (long long)b * CAP;
    const int half = lane >> 5, cl = lane & 31;

    for (unsigned off = (unsigned)w * 64u; off < cnt; off += 256u) {
        const unsigned e = off + (unsigned)lane;
        const bool v = e < cnt;
        int s = 0, dl = 0;
        if (v) { const unsigned p = bkt[base + e]; s = (int)(p & 0xFFFFu); dl = (int)(p >> 16); }
        const int d = b * G + dl;

        // ---- layer 1: h1 = relu(Q[s] + (pos_s - pos_d) @ W1p) ----
        float h1[HID];
        const float4* q4 = (const float4*)(qagg + (long long)s * F_OUT);
        #pragma unroll
        for (int c = 0; c < HID / 4; ++c) {
            const float4 vv = q4[c];
            h1[4*c] = vv.x; h1[4*c+1] = vv.y; h1[4*c+2] = vv.z; h1[4*c+3] = vv.w;
        }
        {
            float pd[3];
            #pragma unroll
            for (int a = 0; a < 3; ++a)
                pd[a] = pos[s * 3 + a] - pos[d * 3 + a];
            #pragma unroll
            for (int a = 0; a < 3; ++a) {
                const float* wr = W1p + a * HID;    // wave-uniform
                #pragma unroll
                for (int k = 0; k < HID; ++k) h1[k] = fmaf(pd[a], wr[k], h1[k]);
            }
        }
        #pragma unroll
        for (int k = 0; k < HID; ++k) h1[k] = fmaxf(h1[k], 0.f);

        // ---- layer 2 (fully unrolled, h1 static-indexed in registers) ----
        float acc[HID];
        #pragma unroll
        for (int k = 0; k < HID; ++k) acc[k] = b2[k];
        #pragma unroll
        for (int j = 0; j < HID; ++j) {
            const float m = h1[j];
            const float* wr = W2 + j * HID;         // wave-uniform
            #pragma unroll
            for (int k = 0; k < HID; ++k) acc[k] = fmaf(m, wr[k], acc[k]);
        }

        // ---- relu + transpose + LDS-atomic aggregate, 2 channel-phases ----
        #pragma unroll
        for (int ph = 0; ph < 2; ++ph) {
            const int c0 = ph * 32;
            #pragma unroll
            for (int k = 0; k < 32; ++k)
                wb[lane * 33 + k] = fmaxf(acc[c0 + k], 0.f);
            __builtin_amdgcn_wave_barrier();
            #pragma unroll 1
            for (int e2 = 0; e2 < 64; e2 += 2) {     // 2 edges/iter (half-waves)
                if (off + (unsigned)e2 >= cnt) break;       // wave-uniform
                const int ee = e2 + half;
                const int dle = __shfl(dl, ee, 64);
                const float h = wb[ee * 33 + cl];
                if (off + (unsigned)ee < cnt)
                    atomicMax(&aggs[dle * HID + c0 + cl], __float_as_uint(h));
            }
            __builtin_amdgcn_wave_barrier();
        }
    }
    __syncthreads();

    // ---- plain coalesced store of the block-owned agg rows ----
    for (int i = t; i < G * HID; i += 256) {
        const int row = i >> 6, ch = i & 63, n = b * G + row;
        if (n < N_NODES)
            out[(long long)n * F_OUT + HID + ch] = __uint_as_float(aggs[i]);
    }
}

// ---------------------------------------------------------------------------
// Kernel D: overflow fixup (runs after gather; count ~0 in practice).
// Full per-thread MLP + global atomicMax against the computed agg rows.
// ---------------------------------------------------------------------------
__global__ __launch_bounds__(64) void ovf_kernel(
    const float* __restrict__ qagg, const float* __restrict__ pos,
    const unsigned* __restrict__ bcur, const unsigned* __restrict__ ovf,
    const float* __restrict__ W1p, const float* __restrict__ W2,
    const float* __restrict__ b2, unsigned* __restrict__ aggbits)
{
    const unsigned n = min(bcur[NB], (unsigned)OVF_CAP);
    for (unsigned i = blockIdx.x * 64 + threadIdx.x; i < n; i += gridDim.x * 64) {
        const unsigned p = ovf[i];
        const int s = (int)(p & 0xFFFFu), d = (int)(p >> 16);
        float h1[HID];
        #pragma unroll 1
        for (int k = 0; k < HID; ++k) h1[k] = qagg[(long long)s * F_OUT + k];
        #pragma unroll 1
        for (int a = 0; a < 3; ++a) {
            const float pd = pos[s * 3 + a] - pos[d * 3 + a];
            #pragma unroll 1
            for (int k = 0; k < HID; ++k) h1[k] = fmaf(pd, W1p[a * HID + k], h1[k]);
        }
        #pragma unroll 1
        for (int k = 0; k < HID; ++k) h1[k] = fmaxf(h1[k], 0.f);
        unsigned* ap = aggbits + (long long)d * F_OUT + HID;
        #pragma unroll 1
        for (int k = 0; k < HID; ++k) {
            float a2 = b2[k];
            #pragma unroll 1
            for (int j = 0; j < HID; ++j) a2 = fmaf(h1[j], W2[j * HID + k], a2);
            a2 = fmaxf(a2, 0.f);
            atomicMax(ap + k, __float_as_uint(a2));
        }
    }
}

// ---------------------------------------------------------------------------
// Kernel E: out[n] = agg[n] @ Wg + bg, in place (wave per node, Wg columns in
// registers, agg broadcast via shfl; wave-internal read->write is race-free).
// ---------------------------------------------------------------------------
__global__ __launch_bounds__(256) void out_gemm_kernel(
    float* __restrict__ out,            // [N_NODES, 128]
    const float* __restrict__ Wg,       // [HID, F_OUT]
    const float* __restrict__ bg)       // [F_OUT]
{
    const int lane = threadIdx.x & 63;
    const int wave = blockIdx.x * (blockDim.x >> 6) + (threadIdx.x >> 6);
    const int nwav = gridDim.x * (blockDim.x >> 6);

    float w1r[HID], w2r[HID];
    #pragma unroll
    for (int j = 0; j < HID; ++j) {
        w1r[j] = Wg[j * F_OUT + lane];
        w2r[j] = Wg[j * F_OUT + 64 + lane];
    }
    const float bga = bg[lane];
    const float bgb = bg[64 + lane];

    for (int n = wave; n < N_NODES; n += nwav) {
        float* row = out + (long long)n * F_OUT;
        const float a = row[64 + lane];
        float y1 = bga, y2 = bgb;
        #pragma unroll
        for (int j = 0; j < HID; ++j) {
            const float aj = __shfl(a, j, 64);
            y1 = fmaf(aj, w1r[j], y1);
            y2 = fmaf(aj, w2r[j], y2);
        }
        row[lane]      = y1;
        row[64 + lane] = y2;
    }
}

extern "C" void kernel_launch(void* const* d_in, const int* in_sizes, int n_in,
                              void* d_out, int out_size, void* d_ws, size_t ws_size,
                              hipStream_t stream) {
    const float* x   = (const float*)d_in[0];
    const float* pos = (const float*)d_in[1];
    const int*   ei  = (const int*)d_in[2];    // harness delivers integers as int32
    const float* W1  = (const float*)d_in[3];
    const float* b1  = (const float*)d_in[4];
    const float* W2  = (const float*)d_in[5];
    const float* b2  = (const float*)d_in[6];
    const float* Wg  = (const float*)d_in[7];
    const float* bg  = (const float*)d_in[8];
    float* out = (float*)d_out;

    unsigned* ws   = (unsigned*)d_ws;          // ~8.7 MB used
    unsigned* bcur = ws;                       // [NB+1]
    unsigned* ovf  = ws + OFF_OVF;             // [OVF_CAP]
    unsigned* bkt  = ws + OFF_BKT;             // [NB*CAP]

    // A: Q + cursor zeroing
    node_pre_kernel<<<(N_NODES + 255) / 256, 256, 0, stream>>>(x, W1, b1, out, bcur);
    // B: single-pass coarse bucketing by dst
    scatter_kernel<<<(N_TOTAL + 255) / 256, 256, 0, stream>>>(ei, bcur, bkt, ovf);
    // C: fused MLP + block-owned LDS segment-max, plain stores
    gather_kernel<<<NB, 256, 0, stream>>>(
        out, pos, bcur, bkt, W1 + F_IN * HID, W2, b2, out);
    // D: overflow fixup (no-op in practice)
    ovf_kernel<<<32, 64, 0, stream>>>(
        out, pos, bcur, ovf, W1 + F_IN * HID, W2, b2, (unsigned*)out);
    // E: out = agg @ Wg + bg, in place
    out_gemm_kernel<<<512, 256, 0, stream>>>(out, Wg, bg);
}

// Round 6
// 792.705 us; speedup vs baseline: 6.3008x; 6.3008x over previous
//
#include <hip/hip_runtime.h>

#define N_NODES 50000
#define N_EDGES 1600000
#define N_TOTAL (N_EDGES + N_NODES)   // edges + self loops
#define F_IN    32
#define HID     64
#define F_OUT   128
#define G       32                    // dst nodes per bucket
#define NB      1563                  // ceil(N_NODES / G)
#define CAP     1344                  // mean 1056 + 9 sigma
#define OVF_CAP 65536

// workspace layout (unsigned units):
//   bcur  [NB+1]   (bcur[NB] = overflow counter)
//   ovf   [OVF_CAP]        at offset 2048
//   bkt   [NB*CAP]         at offset 2048+OVF_CAP   (~8.7 MB total)
#define OFF_OVF 2048
#define OFF_BKT (2048 + OVF_CAP)

// ---------------------------------------------------------------------------
// Kernel A: Q[n] = b1 + x_n @ W1[0:32,:] into d_out cols 0-63 (cols 64-127
// are fully overwritten by gather - no zeroing needed). Also zero bucket
// cursors (ws is re-poisoned 0xAA before every call).
// ---------------------------------------------------------------------------
__global__ __launch_bounds__(256) void node_pre_kernel(
    const float* __restrict__ x,
    const float* __restrict__ W1, const float* __restrict__ b1,
    float* __restrict__ out, unsigned* __restrict__ bcur)
{
    const int n = blockIdx.x * 256 + threadIdx.x;
    if (n <= NB) bcur[n] = 0u;          // NB cursors + overflow counter
    if (n >= N_NODES) return;

    float acc[HID];
    #pragma unroll
    for (int k = 0; k < HID; ++k) acc[k] = b1[k];

    const float4* x4 = (const float4*)(x + (long long)n * F_IN);
    #pragma unroll 1
    for (int c4 = 0; c4 < F_IN / 4; ++c4) {
        const float4 v = x4[c4];
        const float mv[4] = {v.x, v.y, v.z, v.w};
        #pragma unroll
        for (int q = 0; q < 4; ++q) {
            const float* w = W1 + (c4 * 4 + q) * HID;   // wave-uniform
            #pragma unroll
            for (int k = 0; k < HID; ++k) acc[k] = fmaf(mv[q], w[k], acc[k]);
        }
    }

    float4* o4 = (float4*)(out + (long long)n * F_OUT);
    #pragma unroll
    for (int k4 = 0; k4 < HID / 4; ++k4)
        o4[k4] = make_float4(acc[4*k4], acc[4*k4+1], acc[4*k4+2], acc[4*k4+3]);
}

// ---------------------------------------------------------------------------
// Kernel B: single-pass bucketing by dst (coarse sort). One atomicAdd on a
// 6 KB hot cursor array + one packed-u32 store per edge. Overflow (>= 9
// sigma, ~never) goes to a list fixed up after gather.
// ---------------------------------------------------------------------------
__global__ __launch_bounds__(256) void scatter_kernel(
    const int* __restrict__ ei, unsigned* __restrict__ bcur,
    unsigned* __restrict__ bkt, unsigned* __restrict__ ovf)
{
    const int gid = blockIdx.x * 256 + threadIdx.x;
    if (gid >= N_TOTAL) return;
    int s, d;
    if (gid < N_EDGES) { s = ei[gid]; d = ei[N_EDGES + gid]; }
    else               { s = d = gid - N_EDGES; }        // self loop
    const int b = d >> 5;
    const unsigned p = atomicAdd(&bcur[b], 1u);
    if (p < CAP) {
        bkt[(long long)b * CAP + p] = ((unsigned)(d & 31) << 16) | (unsigned)s;
    } else {
        const unsigned q = atomicAdd(&bcur[NB], 1u);
        if (q < OVF_CAP) ovf[q] = ((unsigned)d << 16) | (unsigned)s;
    }
}

// ---------------------------------------------------------------------------
// Kernel C: one block per bucket. Edge-per-lane MLP; h1[64] registerized;
// layer 2 computed in TWO 32-CHANNEL PHASES (acc[32] per phase) so the live
// register set is h1[64]+acc[32]+addr ~= 108 VGPR < the 128-VGPR cliff ->
// no scratch spill (round-5 bug: h1[64]+acc[64] ~150 live under a 128 cap
// spilled ~3 GB to scratch). Each phase: relu -> per-wave LDS transpose ->
// block-owned LDS atomicMax. Final agg rows written with plain coalesced
// stores - no global atomics, no load-test fetches.
// LDS 41 KB -> 3 blocks/CU (12 waves/CU).
// ---------------------------------------------------------------------------
__global__ __launch_bounds__(256, 3) void gather_kernel(
    const float* __restrict__ qagg,     // d_out: [N,128] cols 0-63 = Q
    const float* __restrict__ pos,
    const unsigned* __restrict__ bcur,
    const unsigned* __restrict__ bkt,
    const float* __restrict__ W1p,      // W1 rows 32..34, [3, 64]
    const float* __restrict__ W2, const float* __restrict__ b2,
    float* __restrict__ out)
{
    __shared__ unsigned aggs[G * HID];      // 8 KB, block-owned agg
    __shared__ float    tbuf[4 * 64 * 33];  // 33 KB, per-wave transpose bufs
    const int t = threadIdx.x, lane = t & 63, w = t >> 6;
    const int b = blockIdx.x;
    const unsigned cnt = min(bcur[b], (unsigned)CAP);
    float* wb = tbuf + w * (64 * 33);

    for (int i = t; i < G * HID; i += 256) aggs[i] = 0u;
    __syncthreads();

    const long long base = (long long)b * CAP;
    const int half = lane >> 5, cl = lane & 31;

    for (unsigned off = (unsigned)w * 64u; off < cnt; off += 256u) {
        const unsigned e = off + (unsigned)lane;
        const bool v = e < cnt;
        int s = 0, dl = 0;
        if (v) { const unsigned p = bkt[base + e]; s = (int)(p & 0xFFFFu); dl = (int)(p >> 16); }
        const int d = b * G + dl;

        // ---- layer 1: h1 = relu(Q[s] + (pos_s - pos_d) @ W1p) ----
        float h1[HID];
        const float4* q4 = (const float4*)(qagg + (long long)s * F_OUT);
        #pragma unroll
        for (int c = 0; c < HID / 4; ++c) {
            const float4 vv = q4[c];
            h1[4*c] = vv.x; h1[4*c+1] = vv.y; h1[4*c+2] = vv.z; h1[4*c+3] = vv.w;
        }
        {
            float pd[3];
            #pragma unroll
            for (int a = 0; a < 3; ++a)
                pd[a] = pos[s * 3 + a] - pos[d * 3 + a];
            #pragma unroll
            for (int a = 0; a < 3; ++a) {
                const float* wr = W1p + a * HID;    // wave-uniform
                #pragma unroll
                for (int k = 0; k < HID; ++k) h1[k] = fmaf(pd[a], wr[k], h1[k]);
            }
        }
        #pragma unroll
        for (int k = 0; k < HID; ++k) h1[k] = fmaxf(h1[k], 0.f);

        // ---- layer 2 in two 32-channel phases (bounds register pressure) --
        #pragma unroll 1
        for (int ph = 0; ph < 2; ++ph) {
            const int c0 = ph << 5;
            float acc[32];
            #pragma unroll
            for (int k = 0; k < 32; ++k) acc[k] = b2[c0 + k];
            #pragma unroll
            for (int j = 0; j < HID; ++j) {
                const float m = h1[j];
                const float* wr = W2 + j * HID + c0;    // wave-uniform
                #pragma unroll
                for (int k = 0; k < 32; ++k) acc[k] = fmaf(m, wr[k], acc[k]);
            }

            // relu + transpose into per-wave buffer
            #pragma unroll
            for (int k = 0; k < 32; ++k)
                wb[lane * 33 + k] = fmaxf(acc[k], 0.f);
            __builtin_amdgcn_wave_barrier();

            // LDS-atomic aggregate: 2 edges/iter (one per half-wave)
            #pragma unroll 1
            for (int e2 = 0; e2 < 64; e2 += 2) {
                if (off + (unsigned)e2 >= cnt) break;       // wave-uniform
                const int ee = e2 + half;
                const int dle = __shfl(dl, ee, 64);
                const float h = wb[ee * 33 + cl];
                if (off + (unsigned)ee < cnt)
                    atomicMax(&aggs[dle * HID + c0 + cl], __float_as_uint(h));
            }
            __builtin_amdgcn_wave_barrier();
        }
    }
    __syncthreads();

    // ---- plain coalesced store of the block-owned agg rows ----
    for (int i = t; i < G * HID; i += 256) {
        const int row = i >> 6, ch = i & 63, n = b * G + row;
        if (n < N_NODES)
            out[(long long)n * F_OUT + HID + ch] = __uint_as_float(aggs[i]);
    }
}

// ---------------------------------------------------------------------------
// Kernel D: overflow fixup (runs after gather; count ~0 in practice).
// Full per-thread MLP + global atomicMax against the computed agg rows.
// ---------------------------------------------------------------------------
__global__ __launch_bounds__(64) void ovf_kernel(
    const float* __restrict__ qagg, const float* __restrict__ pos,
    const unsigned* __restrict__ bcur, const unsigned* __restrict__ ovf,
    const float* __restrict__ W1p, const float* __restrict__ W2,
    const float* __restrict__ b2, unsigned* __restrict__ aggbits)
{
    const unsigned n = min(bcur[NB], (unsigned)OVF_CAP);
    for (unsigned i = blockIdx.x * 64 + threadIdx.x; i < n; i += gridDim.x * 64) {
        const unsigned p = ovf[i];
        const int s = (int)(p & 0xFFFFu), d = (int)(p >> 16);
        float h1[HID];
        #pragma unroll 1
        for (int k = 0; k < HID; ++k) h1[k] = qagg[(long long)s * F_OUT + k];
        #pragma unroll 1
        for (int a = 0; a < 3; ++a) {
            const float pd = pos[s * 3 + a] - pos[d * 3 + a];
            #pragma unroll 1
            for (int k = 0; k < HID; ++k) h1[k] = fmaf(pd, W1p[a * HID + k], h1[k]);
        }
        #pragma unroll 1
        for (int k = 0; k < HID; ++k) h1[k] = fmaxf(h1[k], 0.f);
        unsigned* ap = aggbits + (long long)d * F_OUT + HID;
        #pragma unroll 1
        for (int k = 0; k < HID; ++k) {
            float a2 = b2[k];
            #pragma unroll 1
            for (int j = 0; j < HID; ++j) a2 = fmaf(h1[j], W2[j * HID + k], a2);
            a2 = fmaxf(a2, 0.f);
            atomicMax(ap + k, __float_as_uint(a2));
        }
    }
}

// ---------------------------------------------------------------------------
// Kernel E: out[n] = agg[n] @ Wg + bg, in place (wave per node, Wg columns in
// registers, agg broadcast via shfl; wave-internal read->write is race-free).
// ---------------------------------------------------------------------------
__global__ __launch_bounds__(256) void out_gemm_kernel(
    float* __restrict__ out,            // [N_NODES, 128]
    const float* __restrict__ Wg,       // [HID, F_OUT]
    const float* __restrict__ bg)       // [F_OUT]
{
    const int lane = threadIdx.x & 63;
    const int wave = blockIdx.x * (blockDim.x >> 6) + (threadIdx.x >> 6);
    const int nwav = gridDim.x * (blockDim.x >> 6);

    float w1r[HID], w2r[HID];
    #pragma unroll
    for (int j = 0; j < HID; ++j) {
        w1r[j] = Wg[j * F_OUT + lane];
        w2r[j] = Wg[j * F_OUT + 64 + lane];
    }
    const float bga = bg[lane];
    const float bgb = bg[64 + lane];

    for (int n = wave; n < N_NODES; n += nwav) {
        float* row = out + (long long)n * F_OUT;
        const float a = row[64 + lane];
        float y1 = bga, y2 = bgb;
        #pragma unroll
        for (int j = 0; j < HID; ++j) {
            const float aj = __shfl(a, j, 64);
            y1 = fmaf(aj, w1r[j], y1);
            y2 = fmaf(aj, w2r[j], y2);
        }
        row[lane]      = y1;
        row[64 + lane] = y2;
    }
}

extern "C" void kernel_launch(void* const* d_in, const int* in_sizes, int n_in,
                              void* d_out, int out_size, void* d_ws, size_t ws_size,
                              hipStream_t stream) {
    const float* x   = (const float*)d_in[0];
    const float* pos = (const float*)d_in[1];
    const int*   ei  = (const int*)d_in[2];    // harness delivers integers as int32
    const float* W1  = (const float*)d_in[3];
    const float* b1  = (const float*)d_in[4];
    const float* W2  = (const float*)d_in[5];
    const float* b2  = (const float*)d_in[6];
    const float* Wg  = (const float*)d_in[7];
    const float* bg  = (const float*)d_in[8];
    float* out = (float*)d_out;

    unsigned* ws   = (unsigned*)d_ws;          // ~8.7 MB used
    unsigned* bcur = ws;                       // [NB+1]
    unsigned* ovf  = ws + OFF_OVF;             // [OVF_CAP]
    unsigned* bkt  = ws + OFF_BKT;             // [NB*CAP]

    // A: Q + cursor zeroing
    node_pre_kernel<<<(N_NODES + 255) / 256, 256, 0, stream>>>(x, W1, b1, out, bcur);
    // B: single-pass coarse bucketing by dst
    scatter_kernel<<<(N_TOTAL + 255) / 256, 256, 0, stream>>>(ei, bcur, bkt, ovf);
    // C: fused MLP + block-owned LDS segment-max, plain stores
    gather_kernel<<<NB, 256, 0, stream>>>(
        out, pos, bcur, bkt, W1 + F_IN * HID, W2, b2, out);
    // D: overflow fixup (no-op in practice)
    ovf_kernel<<<32, 64, 0, stream>>>(
        out, pos, bcur, ovf, W1 + F_IN * HID, W2, b2, (unsigned*)out);
    // E: out = agg @ Wg + bg, in place
    out_gemm_kernel<<<512, 256, 0, stream>>>(out, Wg, bg);
}

// Round 8
// 349.932 us; speedup vs baseline: 14.2732x; 2.2653x over previous
//
#include <hip/hip_runtime.h>

#define N_NODES 50000
#define N_EDGES 1600000
#define N_TOTAL (N_EDGES + N_NODES)   // edges + self loops
#define F_IN    32
#define HID     64
#define F_OUT   128
#define G       32                    // dst nodes per bucket
#define NB      1563                  // ceil(N_NODES / G)
#define CAP_MAX 1280                  // mean 1056 + ~7 sigma
#define OVF_CAP 16384

// workspace layout (u32 units):
//   qbf  [N_NODES*32]  packed bf16 Q rows (dense 6.4 MB -> L2-resident)
//   bcur [NB*16+16]    cursors padded to 64B lines (last = ovf counter)
//   ovf  [OVF_CAP]
//   bkt  [NB*cap]      cap chosen at launch from ws_size (overflow correct)
#define OFF_QBF  0
#define OFF_BCUR (N_NODES * 32)
#define OFF_OVF  (OFF_BCUR + NB * 16 + 16)
#define OFF_BKT  (OFF_OVF + OVF_CAP)

typedef __attribute__((ext_vector_type(8))) short short8;  // 8 bf16 (4 VGPRs)
typedef __attribute__((ext_vector_type(4))) float v4f;

__device__ __forceinline__ unsigned f2bf2(float a, float b) {   // pack 2 bf16 (RNE)
    unsigned ua = __float_as_uint(a), ub = __float_as_uint(b);
    ua = (ua + 0x7FFFu + ((ua >> 16) & 1u)) >> 16;
    ub = (ub + 0x7FFFu + ((ub >> 16) & 1u)) & 0xFFFF0000u;
    return ua | ub;
}

// ---------------------------------------------------------------------------
// Kernel A: Q[n] = b1 + x_n @ W1[0:32,:], packed to bf16 in ws (dense 6.4 MB).
// Also zeroes the padded bucket cursors.
// ---------------------------------------------------------------------------
__global__ __launch_bounds__(256) void node_pre_kernel(
    const float* __restrict__ x,
    const float* __restrict__ W1, const float* __restrict__ b1,
    unsigned* __restrict__ qbf, unsigned* __restrict__ bcur)
{
    const int n = blockIdx.x * 256 + threadIdx.x;
    if (n < NB * 16 + 16) bcur[n] = 0u;
    if (n >= N_NODES) return;

    float acc[HID];
    #pragma unroll
    for (int k = 0; k < HID; ++k) acc[k] = b1[k];

    const float4* x4 = (const float4*)(x + (long long)n * F_IN);
    #pragma unroll 1
    for (int c4 = 0; c4 < F_IN / 4; ++c4) {
        const float4 v = x4[c4];
        const float mv[4] = {v.x, v.y, v.z, v.w};
        #pragma unroll
        for (int qq = 0; qq < 4; ++qq) {
            const float* w = W1 + (c4 * 4 + qq) * HID;   // wave-uniform
            #pragma unroll
            for (int k = 0; k < HID; ++k) acc[k] = fmaf(mv[qq], w[k], acc[k]);
        }
    }

    uint4* o4 = (uint4*)(qbf + (unsigned)n * 32u);
    #pragma unroll
    for (int j4 = 0; j4 < 8; ++j4)
        o4[j4] = make_uint4(f2bf2(acc[j4*8+0], acc[j4*8+1]),
                            f2bf2(acc[j4*8+2], acc[j4*8+3]),
                            f2bf2(acc[j4*8+4], acc[j4*8+5]),
                            f2bf2(acc[j4*8+6], acc[j4*8+7]));
}

// ---------------------------------------------------------------------------
// Kernel B: single-pass bucketing by dst. Cursors padded to one 64B line each
// -> 1563 independent atomic chains.
// ---------------------------------------------------------------------------
__global__ __launch_bounds__(256) void scatter_kernel(
    const int* __restrict__ ei, unsigned* __restrict__ bcur,
    unsigned* __restrict__ bkt, unsigned* __restrict__ ovf, int cap)
{
    const int gid = blockIdx.x * 256 + threadIdx.x;
    if (gid >= N_TOTAL) return;
    int s, d;
    if (gid < N_EDGES) { s = ei[gid]; d = ei[N_EDGES + gid]; }
    else               { s = d = gid - N_EDGES; }        // self loop
    const int b = d >> 5;
    const unsigned p = atomicAdd(&bcur[b * 16], 1u);
    if (p < (unsigned)cap) {
        bkt[(long long)b * cap + p] = ((unsigned)(d & 31) << 16) | (unsigned)s;
    } else {
        const unsigned qo = atomicAdd(&bcur[NB * 16], 1u);
        if (qo < OVF_CAP) ovf[qo] = ((unsigned)d << 16) | (unsigned)s;
    }
}

// ---------------------------------------------------------------------------
// Kernel C: one block (4 waves) per bucket. Per wave-batch of 64 edges:
// layer1 fp32 (bf16 Q gather + pos part) -> bf16 A-fragments staged in
// per-wave LDS -> layer2 = 32x mfma_f32_16x16x32_bf16 -> +b2, relu, LDS
// atomicMax into block-owned agg -> plain coalesced store.
// ROUND-8 FIX: all cross-lane LDS handoffs are fenced with __syncthreads()
// (round 7 used wave_barrier only = compiler fence, NO hw s_waitcnt -> the
// intra-wave ds_write_b128 -> other-lane ds_read_b128 RAW/WAR raced
// intermittently, diverging under replay load). Batch loop made
// block-uniform (nit iterations for all waves) so barriers are legal.
// ---------------------------------------------------------------------------
__global__ __launch_bounds__(256, 4) void gather_kernel(
    const unsigned* __restrict__ qbf,   // [N,32] packed bf16 Q
    const float* __restrict__ pos,
    const unsigned* __restrict__ bcur,
    const unsigned* __restrict__ bkt,
    const float* __restrict__ W1p,      // W1 rows 32..34, [3, 64]
    const float* __restrict__ W2, const float* __restrict__ b2,
    float* __restrict__ out, int cap)
{
    __shared__ unsigned aggs[G * HID];      // 8 KB block-owned agg
    __shared__ unsigned w2t[64 * 36];       // 9 KB: W2^T bf16, row n, stride 36 u32
    __shared__ unsigned ast[4][64 * 20];    // 20 KB: per-wave A-stage (k-half)
    __shared__ int      wdl[4][64];         // 1 KB: per-wave dst-locals
    __shared__ float    posd[G * 3];        // bucket nodes' pos

    const int t = threadIdx.x, lane = t & 63, w = t >> 6;
    const int q = lane >> 4, m15 = lane & 15;
    const int b = blockIdx.x;
    const unsigned cnt = min(bcur[b * 16], (unsigned)cap);

    for (int i = t; i < G * HID; i += 256) aggs[i] = 0u;
    for (int i = t; i < 64 * 32; i += 256) {            // W2^T -> bf16 LDS
        const int n = i >> 5, ku = i & 31;              // k-pair index
        w2t[n * 36 + ku] = f2bf2(W2[(2 * ku) * HID + n], W2[(2 * ku + 1) * HID + n]);
    }
    for (int i = t; i < G * 3; i += 256) {
        const int node = b * G + i / 3;
        posd[i] = (node < N_NODES) ? pos[node * 3 + i % 3] : 0.f;
    }
    __syncthreads();

    float b2v[4];
    #pragma unroll
    for (int nt = 0; nt < 4; ++nt) b2v[nt] = b2[nt * 16 + m15];

    unsigned* aw = ast[w];
    int* wd = wdl[w];
    const long long base = (long long)b * cap;
    const unsigned nit = (cnt + 255u) >> 8;     // block-uniform iteration count

    #pragma unroll 1
    for (unsigned it = 0; it < nit; ++it) {
        const unsigned off = it * 256u + (unsigned)w * 64u;
        const unsigned rem = (off < cnt) ? min(64u, cnt - off) : 0u;
        const unsigned e = off + (unsigned)lane;
        int s = 0, dl = 0;
        if (e < cnt) { const unsigned p = bkt[base + e]; s = (int)(p & 0xFFFFu); dl = (int)(p >> 16); }
        wd[lane] = dl;

        // Q row: 8 x b128 issued up front (outstanding during layer-1 compute)
        const uint4* qr = (const uint4*)(qbf + (unsigned)s * 32u);
        uint4 qv[8];
        #pragma unroll
        for (int i = 0; i < 8; ++i) qv[i] = qr[i];

        const float pd0 = pos[s * 3 + 0] - posd[dl * 3 + 0];
        const float pd1 = pos[s * 3 + 1] - posd[dl * 3 + 1];
        const float pd2 = pos[s * 3 + 2] - posd[dl * 3 + 2];

        short8 a0[4], a1[4];
        #pragma unroll
        for (int hf = 0; hf < 2; ++hf) {
            const int c0 = hf * 32;
            float hc[32];
            #pragma unroll
            for (int j4 = 0; j4 < 4; ++j4) {
                const uint4 v = qv[hf * 4 + j4];
                const unsigned uu[4] = {v.x, v.y, v.z, v.w};
                #pragma unroll
                for (int p2 = 0; p2 < 4; ++p2) {
                    hc[j4 * 8 + p2 * 2    ] = __uint_as_float(uu[p2] << 16);
                    hc[j4 * 8 + p2 * 2 + 1] = __uint_as_float(uu[p2] & 0xFFFF0000u);
                }
            }
            #pragma unroll
            for (int k = 0; k < 32; ++k) {
                float v = hc[k];
                v = fmaf(pd0, W1p[0 * HID + c0 + k], v);    // wave-uniform
                v = fmaf(pd1, W1p[1 * HID + c0 + k], v);
                v = fmaf(pd2, W1p[2 * HID + c0 + k], v);
                hc[k] = fmaxf(v, 0.f);
            }
            // pack + stage in A-frag order: row=edge(lane), 16 u32, stride 20
            uint4* dst = (uint4*)(aw + lane * 20);
            #pragma unroll
            for (int j4 = 0; j4 < 4; ++j4)
                dst[j4] = make_uint4(f2bf2(hc[j4*8+0], hc[j4*8+1]),
                                     f2bf2(hc[j4*8+2], hc[j4*8+3]),
                                     f2bf2(hc[j4*8+4], hc[j4*8+5]),
                                     f2bf2(hc[j4*8+6], hc[j4*8+7]));
            __syncthreads();                    // stage-write -> cross-lane read
            short8* af = hf ? a1 : a0;
            #pragma unroll
            for (int mt = 0; mt < 4; ++mt)
                af[mt] = *(const short8*)(aw + (mt * 16 + m15) * 20 + q * 4);
            __syncthreads();                    // read done -> next overwrite ok
        }

        // ---- MFMA layer 2 + epilogue, in two 32-channel halves ----
        #pragma unroll
        for (int h = 0; h < 2; ++h) {
            short8 bf[2][2];    // [ntl][ks]
            #pragma unroll
            for (int ntl = 0; ntl < 2; ++ntl)
                #pragma unroll
                for (int ks = 0; ks < 2; ++ks)
                    bf[ntl][ks] = *(const short8*)(
                        w2t + ((2 * h + ntl) * 16 + m15) * 36 + ks * 16 + q * 4);
            v4f c[4][2] = {};
            #pragma unroll
            for (int mt = 0; mt < 4; ++mt)
                #pragma unroll
                for (int ntl = 0; ntl < 2; ++ntl) {
                    c[mt][ntl] = __builtin_amdgcn_mfma_f32_16x16x32_bf16(
                        a0[mt], bf[ntl][0], c[mt][ntl], 0, 0, 0);
                    c[mt][ntl] = __builtin_amdgcn_mfma_f32_16x16x32_bf16(
                        a1[mt], bf[ntl][1], c[mt][ntl], 0, 0, 0);
                }
            #pragma unroll
            for (int mt = 0; mt < 4; ++mt) {
                #pragma unroll
                for (int r = 0; r < 4; ++r) {
                    const int er = mt * 16 + q * 4 + r;   // edge index in batch
                    const int dle = wd[er];
                    const bool vv = (unsigned)er < rem;
                    #pragma unroll
                    for (int ntl = 0; ntl < 2; ++ntl) {
                        const int nt = 2 * h + ntl;
                        const float hv = fmaxf(c[mt][ntl][r] + b2v[nt], 0.f);
                        if (vv)
                            atomicMax(&aggs[dle * HID + nt * 16 + m15],
                                      __float_as_uint(hv));
                    }
                }
            }
        }
        __syncthreads();    // epilogue wd/agg reads done -> next wd write ok
    }
    __syncthreads();

    for (int i = t; i < G * HID; i += 256) {
        const int row = i >> 6, ch = i & 63, n = b * G + row;
        if (n < N_NODES)
            out[(long long)n * F_OUT + HID + ch] = __uint_as_float(aggs[i]);
    }
}

// ---------------------------------------------------------------------------
// Kernel D: overflow fixup (~0 edges in practice; correct for any count).
// ---------------------------------------------------------------------------
__global__ __launch_bounds__(64) void ovf_kernel(
    const unsigned* __restrict__ qbf, const float* __restrict__ pos,
    const unsigned* __restrict__ bcur, const unsigned* __restrict__ ovf,
    const float* __restrict__ W1p, const float* __restrict__ W2,
    const float* __restrict__ b2, unsigned* __restrict__ aggbits)
{
    const unsigned n = min(bcur[NB * 16], (unsigned)OVF_CAP);
    for (unsigned i = blockIdx.x * 64 + threadIdx.x; i < n; i += gridDim.x * 64) {
        const unsigned p = ovf[i];
        const int s = (int)(p & 0xFFFFu), d = (int)(p >> 16);
        float h1[HID];
        #pragma unroll 1
        for (int k = 0; k < HID; ++k) {
            const unsigned u = qbf[s * 32 + (k >> 1)];
            h1[k] = (k & 1) ? __uint_as_float(u & 0xFFFF0000u)
                            : __uint_as_float(u << 16);
        }
        #pragma unroll 1
        for (int a = 0; a < 3; ++a) {
            const float pd = pos[s * 3 + a] - pos[d * 3 + a];
            #pragma unroll 1
            for (int k = 0; k < HID; ++k) h1[k] = fmaf(pd, W1p[a * HID + k], h1[k]);
        }
        // match the MFMA path's numerics: relu then round h1 to bf16
        #pragma unroll 1
        for (int k = 0; k < HID; ++k) {
            const unsigned hb = f2bf2(fmaxf(h1[k], 0.f), 0.f) << 16;
            h1[k] = __uint_as_float(hb);
        }
        unsigned* ap = aggbits + (long long)d * F_OUT + HID;
        #pragma unroll 1
        for (int k = 0; k < HID; ++k) {
            float a2 = b2[k];
            #pragma unroll 1
            for (int j = 0; j < HID; ++j) {
                const float w2b = __uint_as_float(f2bf2(W2[j * HID + k], 0.f) << 16);
                a2 = fmaf(h1[j], w2b, a2);
            }
            a2 = fmaxf(a2, 0.f);
            atomicMax(ap + k, __float_as_uint(a2));
        }
    }
}

// ---------------------------------------------------------------------------
// Kernel E: out[n] = agg[n] @ Wg + bg, in place (wave per node, Wg columns in
// registers, agg broadcast via shfl; wave-internal read->write is race-free).
// ---------------------------------------------------------------------------
__global__ __launch_bounds__(256) void out_gemm_kernel(
    float* __restrict__ out,            // [N_NODES, 128]
    const float* __restrict__ Wg,       // [HID, F_OUT]
    const float* __restrict__ bg)       // [F_OUT]
{
    const int lane = threadIdx.x & 63;
    const int wave = blockIdx.x * (blockDim.x >> 6) + (threadIdx.x >> 6);
    const int nwav = gridDim.x * (blockDim.x >> 6);

    float w1r[HID], w2r[HID];
    #pragma unroll
    for (int j = 0; j < HID; ++j) {
        w1r[j] = Wg[j * F_OUT + lane];
        w2r[j] = Wg[j * F_OUT + 64 + lane];
    }
    const float bga = bg[lane];
    const float bgb = bg[64 + lane];

    for (int n = wave; n < N_NODES; n += nwav) {
        float* row = out + (long long)n * F_OUT;
        const float a = row[64 + lane];
        float y1 = bga, y2 = bgb;
        #pragma unroll
        for (int j = 0; j < HID; ++j) {
            const float aj = __shfl(a, j, 64);
            y1 = fmaf(aj, w1r[j], y1);
            y2 = fmaf(aj, w2r[j], y2);
        }
        row[lane]      = y1;
        row[64 + lane] = y2;
    }
}

extern "C" void kernel_launch(void* const* d_in, const int* in_sizes, int n_in,
                              void* d_out, int out_size, void* d_ws, size_t ws_size,
                              hipStream_t stream) {
    const float* x   = (const float*)d_in[0];
    const float* pos = (const float*)d_in[1];
    const int*   ei  = (const int*)d_in[2];    // harness delivers integers as int32
    const float* W1  = (const float*)d_in[3];
    const float* b1  = (const float*)d_in[4];
    const float* W2  = (const float*)d_in[5];
    const float* b2  = (const float*)d_in[6];
    const float* Wg  = (const float*)d_in[7];
    const float* bg  = (const float*)d_in[8];
    float* out = (float*)d_out;

    unsigned* ws   = (unsigned*)d_ws;
    unsigned* qbf  = ws + OFF_QBF;
    unsigned* bcur = ws + OFF_BCUR;
    unsigned* ovf  = ws + OFF_OVF;
    unsigned* bkt  = ws + OFF_BKT;

    // bucket capacity from available workspace (overflow path correct anyway)
    long long avail = (long long)(ws_size / 4) - OFF_BKT;
    int cap = (int)(avail / NB);
    if (cap > CAP_MAX) cap = CAP_MAX;
    if (cap < 64) cap = 64;

    node_pre_kernel<<<(N_NODES + 255) / 256, 256, 0, stream>>>(x, W1, b1, qbf, bcur);
    scatter_kernel<<<(N_TOTAL + 255) / 256, 256, 0, stream>>>(ei, bcur, bkt, ovf, cap);
    gather_kernel<<<NB, 256, 0, stream>>>(
        qbf, pos, bcur, bkt, W1 + F_IN * HID, W2, b2, out, cap);
    ovf_kernel<<<32, 64, 0, stream>>>(
        qbf, pos, bcur, ovf, W1 + F_IN * HID, W2, b2, (unsigned*)out);
    out_gemm_kernel<<<512, 256, 0, stream>>>(out, Wg, bg);
}

// Round 9
// 346.521 us; speedup vs baseline: 14.4137x; 1.0098x over previous
//
#include <hip/hip_runtime.h>

#define N_NODES 50000
#define N_EDGES 1600000
#define N_TOTAL (N_EDGES + N_NODES)   // edges + self loops
#define F_IN    32
#define HID     64
#define F_OUT   128
#define G       32                    // dst nodes per bucket
#define NB      1563                  // ceil(N_NODES / G)
#define SUB     8                     // sub-lists per bucket (atomic-chain split)
#define CAPX_MAX 224                  // per (bucket,sub): mean 132 + ~8 sigma
#define OVF_CAP 16384

// workspace layout (u32 units):
//   qbf  [N_NODES*32]     packed bf16 Q rows (dense 6.4 MB)
//   bcur [NB*SUB*16+16]   each sub-cursor on its own 64B line; last = ovf ctr
//   ovf  [OVF_CAP]
//   bkt  [NB*SUB*capx]    capx chosen at launch from ws_size
#define OFF_QBF  0
#define OFF_BCUR (N_NODES * 32)
#define NCUR     (NB * SUB * 16 + 16)
#define OFF_OVF  (OFF_BCUR + NCUR)
#define OFF_BKT  (OFF_OVF + OVF_CAP)

typedef __attribute__((ext_vector_type(8))) short short8;  // 8 bf16 (4 VGPRs)
typedef __attribute__((ext_vector_type(4))) float v4f;

__device__ __forceinline__ unsigned f2bf2(float a, float b) {   // pack 2 bf16 (RNE)
    unsigned ua = __float_as_uint(a), ub = __float_as_uint(b);
    ua = (ua + 0x7FFFu + ((ua >> 16) & 1u)) >> 16;
    ub = (ub + 0x7FFFu + ((ub >> 16) & 1u)) & 0xFFFF0000u;
    return ua | ub;
}

// ---------------------------------------------------------------------------
// Kernel A: Q[n] = b1 + x_n @ W1[0:32,:], packed to bf16 in ws (dense 6.4 MB).
// Also zeroes the padded sub-cursor array (grid-stride: 200,080 u32).
// ---------------------------------------------------------------------------
__global__ __launch_bounds__(256) void node_pre_kernel(
    const float* __restrict__ x,
    const float* __restrict__ W1, const float* __restrict__ b1,
    unsigned* __restrict__ qbf, unsigned* __restrict__ bcur)
{
    const int n = blockIdx.x * 256 + threadIdx.x;
    const int nthr = gridDim.x * 256;
    for (int i = n; i < NCUR; i += nthr) bcur[i] = 0u;
    if (n >= N_NODES) return;

    float acc[HID];
    #pragma unroll
    for (int k = 0; k < HID; ++k) acc[k] = b1[k];

    const float4* x4 = (const float4*)(x + (long long)n * F_IN);
    #pragma unroll 1
    for (int c4 = 0; c4 < F_IN / 4; ++c4) {
        const float4 v = x4[c4];
        const float mv[4] = {v.x, v.y, v.z, v.w};
        #pragma unroll
        for (int qq = 0; qq < 4; ++qq) {
            const float* w = W1 + (c4 * 4 + qq) * HID;   // wave-uniform
            #pragma unroll
            for (int k = 0; k < HID; ++k) acc[k] = fmaf(mv[qq], w[k], acc[k]);
        }
    }

    uint4* o4 = (uint4*)(qbf + (unsigned)n * 32u);
    #pragma unroll
    for (int j4 = 0; j4 < 8; ++j4)
        o4[j4] = make_uint4(f2bf2(acc[j4*8+0], acc[j4*8+1]),
                            f2bf2(acc[j4*8+2], acc[j4*8+3]),
                            f2bf2(acc[j4*8+4], acc[j4*8+5]),
                            f2bf2(acc[j4*8+6], acc[j4*8+7]));
}

// ---------------------------------------------------------------------------
// Kernel B: single-pass bucketing by dst, cursor split 8 ways per bucket
// (sub-list = gid&7, each sub-cursor on its own 64B line). Round-8 profile:
// one cursor/bucket -> 1056-deep same-address atomic chains ~= 131 us.
// Chain depth now 132.
// ---------------------------------------------------------------------------
__global__ __launch_bounds__(256) void scatter_kernel(
    const int* __restrict__ ei, unsigned* __restrict__ bcur,
    unsigned* __restrict__ bkt, unsigned* __restrict__ ovf, int capx)
{
    const int gid = blockIdx.x * 256 + threadIdx.x;
    if (gid >= N_TOTAL) return;
    int s, d;
    if (gid < N_EDGES) { s = ei[gid]; d = ei[N_EDGES + gid]; }
    else               { s = d = gid - N_EDGES; }        // self loop
    const int b = d >> 5;
    const int cell = b * SUB + (gid & (SUB - 1));
    const unsigned p = atomicAdd(&bcur[cell * 16], 1u);
    if (p < (unsigned)capx) {
        bkt[(long long)cell * capx + p] = ((unsigned)(d & 31) << 16) | (unsigned)s;
    } else {
        const unsigned qo = atomicAdd(&bcur[NB * SUB * 16], 1u);
        if (qo < OVF_CAP) ovf[qo] = ((unsigned)d << 16) | (unsigned)s;
    }
}

// ---------------------------------------------------------------------------
// Kernel C: one block (4 waves) per bucket. Reads the bucket's 8 sub-lists
// through a flat index + 9-entry prefix table in LDS; otherwise identical to
// round 8 (layer1 fp32 -> bf16 A-frags in per-wave LDS -> 32x
// mfma_f32_16x16x32_bf16 -> +b2/relu -> block-owned LDS atomicMax -> plain
// coalesced store; all cross-lane LDS handoffs fenced with __syncthreads).
// ---------------------------------------------------------------------------
__global__ __launch_bounds__(256, 4) void gather_kernel(
    const unsigned* __restrict__ qbf,   // [N,32] packed bf16 Q
    const float* __restrict__ pos,
    const unsigned* __restrict__ bcur,
    const unsigned* __restrict__ bkt,
    const float* __restrict__ W1p,      // W1 rows 32..34, [3, 64]
    const float* __restrict__ W2, const float* __restrict__ b2,
    float* __restrict__ out, int capx)
{
    __shared__ unsigned aggs[G * HID];      // 8 KB block-owned agg
    __shared__ unsigned w2t[64 * 36];       // 9 KB: W2^T bf16, row n, stride 36 u32
    __shared__ unsigned ast[4][64 * 20];    // 20 KB: per-wave A-stage (k-half)
    __shared__ int      wdl[4][64];         // 1 KB: per-wave dst-locals
    __shared__ float    posd[G * 3];        // bucket nodes' pos
    __shared__ unsigned Ps[SUB + 1];        // sub-list exclusive prefix

    const int t = threadIdx.x, lane = t & 63, w = t >> 6;
    const int q = lane >> 4, m15 = lane & 15;
    const int b = blockIdx.x;

    if (t == 0) Ps[0] = 0u;
    if (t < SUB) Ps[t + 1] = min(bcur[(b * SUB + t) * 16], (unsigned)capx);
    for (int i = t; i < G * HID; i += 256) aggs[i] = 0u;
    for (int i = t; i < 64 * 32; i += 256) {            // W2^T -> bf16 LDS
        const int n = i >> 5, ku = i & 31;              // k-pair index
        w2t[n * 36 + ku] = f2bf2(W2[(2 * ku) * HID + n], W2[(2 * ku + 1) * HID + n]);
    }
    for (int i = t; i < G * 3; i += 256) {
        const int node = b * G + i / 3;
        posd[i] = (node < N_NODES) ? pos[node * 3 + i % 3] : 0.f;
    }
    __syncthreads();
    if (t == 0) {
        unsigned a = 0;
        #pragma unroll
        for (int i = 1; i <= SUB; ++i) { a += Ps[i]; Ps[i] = a; }
    }
    __syncthreads();

    const unsigned cnt = Ps[SUB];

    float b2v[4];
    #pragma unroll
    for (int nt = 0; nt < 4; ++nt) b2v[nt] = b2[nt * 16 + m15];

    unsigned* aw = ast[w];
    int* wd = wdl[w];
    const long long base = (long long)b * SUB * capx;
    const unsigned nit = (cnt + 255u) >> 8;     // block-uniform iteration count

    #pragma unroll 1
    for (unsigned it = 0; it < nit; ++it) {
        const unsigned off = it * 256u + (unsigned)w * 64u;
        const unsigned rem = (off < cnt) ? min(64u, cnt - off) : 0u;
        const unsigned f = off + (unsigned)lane;
        int s = 0, dl = 0;
        if (f < cnt) {
            int xs = 0;                          // flat index -> (sub-list, pos)
            #pragma unroll
            for (int i = 1; i < SUB; ++i) xs += (f >= Ps[i]);
            const unsigned p = bkt[base + (long long)xs * capx + (f - Ps[xs])];
            s = (int)(p & 0xFFFFu); dl = (int)(p >> 16);
        }
        wd[lane] = dl;

        // Q row: 8 x b128 issued up front (outstanding during layer-1 compute)
        const uint4* qr = (const uint4*)(qbf + (unsigned)s * 32u);
        uint4 qv[8];
        #pragma unroll
        for (int i = 0; i < 8; ++i) qv[i] = qr[i];

        const float pd0 = pos[s * 3 + 0] - posd[dl * 3 + 0];
        const float pd1 = pos[s * 3 + 1] - posd[dl * 3 + 1];
        const float pd2 = pos[s * 3 + 2] - posd[dl * 3 + 2];

        short8 a0[4], a1[4];
        #pragma unroll
        for (int hf = 0; hf < 2; ++hf) {
            const int c0 = hf * 32;
            float hc[32];
            #pragma unroll
            for (int j4 = 0; j4 < 4; ++j4) {
                const uint4 v = qv[hf * 4 + j4];
                const unsigned uu[4] = {v.x, v.y, v.z, v.w};
                #pragma unroll
                for (int p2 = 0; p2 < 4; ++p2) {
                    hc[j4 * 8 + p2 * 2    ] = __uint_as_float(uu[p2] << 16);
                    hc[j4 * 8 + p2 * 2 + 1] = __uint_as_float(uu[p2] & 0xFFFF0000u);
                }
            }
            #pragma unroll
            for (int k = 0; k < 32; ++k) {
                float v = hc[k];
                v = fmaf(pd0, W1p[0 * HID + c0 + k], v);    // wave-uniform
                v = fmaf(pd1, W1p[1 * HID + c0 + k], v);
                v = fmaf(pd2, W1p[2 * HID + c0 + k], v);
                hc[k] = fmaxf(v, 0.f);
            }
            // pack + stage in A-frag order: row=edge(lane), 16 u32, stride 20
            uint4* dst = (uint4*)(aw + lane * 20);
            #pragma unroll
            for (int j4 = 0; j4 < 4; ++j4)
                dst[j4] = make_uint4(f2bf2(hc[j4*8+0], hc[j4*8+1]),
                                     f2bf2(hc[j4*8+2], hc[j4*8+3]),
                                     f2bf2(hc[j4*8+4], hc[j4*8+5]),
                                     f2bf2(hc[j4*8+6], hc[j4*8+7]));
            __syncthreads();                    // stage-write -> cross-lane read
            short8* af = hf ? a1 : a0;
            #pragma unroll
            for (int mt = 0; mt < 4; ++mt)
                af[mt] = *(const short8*)(aw + (mt * 16 + m15) * 20 + q * 4);
            __syncthreads();                    // read done -> next overwrite ok
        }

        // ---- MFMA layer 2 + epilogue, in two 32-channel halves ----
        #pragma unroll
        for (int h = 0; h < 2; ++h) {
            short8 bf[2][2];    // [ntl][ks]
            #pragma unroll
            for (int ntl = 0; ntl < 2; ++ntl)
                #pragma unroll
                for (int ks = 0; ks < 2; ++ks)
                    bf[ntl][ks] = *(const short8*)(
                        w2t + ((2 * h + ntl) * 16 + m15) * 36 + ks * 16 + q * 4);
            v4f c[4][2] = {};
            #pragma unroll
            for (int mt = 0; mt < 4; ++mt)
                #pragma unroll
                for (int ntl = 0; ntl < 2; ++ntl) {
                    c[mt][ntl] = __builtin_amdgcn_mfma_f32_16x16x32_bf16(
                        a0[mt], bf[ntl][0], c[mt][ntl], 0, 0, 0);
                    c[mt][ntl] = __builtin_amdgcn_mfma_f32_16x16x32_bf16(
                        a1[mt], bf[ntl][1], c[mt][ntl], 0, 0, 0);
                }
            #pragma unroll
            for (int mt = 0; mt < 4; ++mt) {
                #pragma unroll
                for (int r = 0; r < 4; ++r) {
                    const int er = mt * 16 + q * 4 + r;   // edge index in batch
                    const int dle = wd[er];
                    const bool vv = (unsigned)er < rem;
                    #pragma unroll
                    for (int ntl = 0; ntl < 2; ++ntl) {
                        const int nt = 2 * h + ntl;
                        const float hv = fmaxf(c[mt][ntl][r] + b2v[nt], 0.f);
                        if (vv)
                            atomicMax(&aggs[dle * HID + nt * 16 + m15],
                                      __float_as_uint(hv));
                    }
                }
            }
        }
        __syncthreads();    // epilogue wd/agg reads done -> next wd write ok
    }
    __syncthreads();

    for (int i = t; i < G * HID; i += 256) {
        const int row = i >> 6, ch = i & 63, n = b * G + row;
        if (n < N_NODES)
            out[(long long)n * F_OUT + HID + ch] = __uint_as_float(aggs[i]);
    }
}

// ---------------------------------------------------------------------------
// Kernel D: overflow fixup (~0 edges in practice; correct for any count).
// Numerics match the MFMA path (h1 and W2 rounded to bf16).
// ---------------------------------------------------------------------------
__global__ __launch_bounds__(64) void ovf_kernel(
    const unsigned* __restrict__ qbf, const float* __restrict__ pos,
    const unsigned* __restrict__ bcur, const unsigned* __restrict__ ovf,
    const float* __restrict__ W1p, const float* __restrict__ W2,
    const float* __restrict__ b2, unsigned* __restrict__ aggbits)
{
    const unsigned n = min(bcur[NB * SUB * 16], (unsigned)OVF_CAP);
    for (unsigned i = blockIdx.x * 64 + threadIdx.x; i < n; i += gridDim.x * 64) {
        const unsigned p = ovf[i];
        const int s = (int)(p & 0xFFFFu), d = (int)(p >> 16);
        float h1[HID];
        #pragma unroll 1
        for (int k = 0; k < HID; ++k) {
            const unsigned u = qbf[s * 32 + (k >> 1)];
            h1[k] = (k & 1) ? __uint_as_float(u & 0xFFFF0000u)
                            : __uint_as_float(u << 16);
        }
        #pragma unroll 1
        for (int a = 0; a < 3; ++a) {
            const float pd = pos[s * 3 + a] - pos[d * 3 + a];
            #pragma unroll 1
            for (int k = 0; k < HID; ++k) h1[k] = fmaf(pd, W1p[a * HID + k], h1[k]);
        }
        #pragma unroll 1
        for (int k = 0; k < HID; ++k) {
            const unsigned hb = f2bf2(fmaxf(h1[k], 0.f), 0.f) << 16;
            h1[k] = __uint_as_float(hb);
        }
        unsigned* ap = aggbits + (long long)d * F_OUT + HID;
        #pragma unroll 1
        for (int k = 0; k < HID; ++k) {
            float a2 = b2[k];
            #pragma unroll 1
            for (int j = 0; j < HID; ++j) {
                const float w2b = __uint_as_float(f2bf2(W2[j * HID + k], 0.f) << 16);
                a2 = fmaf(h1[j], w2b, a2);
            }
            a2 = fmaxf(a2, 0.f);
            atomicMax(ap + k, __float_as_uint(a2));
        }
    }
}

// ---------------------------------------------------------------------------
// Kernel E: out[n] = agg[n] @ Wg + bg, in place (wave per node, Wg columns in
// registers, agg broadcast via shfl; wave-internal read->write is race-free).
// ---------------------------------------------------------------------------
__global__ __launch_bounds__(256) void out_gemm_kernel(
    float* __restrict__ out,            // [N_NODES, 128]
    const float* __restrict__ Wg,       // [HID, F_OUT]
    const float* __restrict__ bg)       // [F_OUT]
{
    const int lane = threadIdx.x & 63;
    const int wave = blockIdx.x * (blockDim.x >> 6) + (threadIdx.x >> 6);
    const int nwav = gridDim.x * (blockDim.x >> 6);

    float w1r[HID], w2r[HID];
    #pragma unroll
    for (int j = 0; j < HID; ++j) {
        w1r[j] = Wg[j * F_OUT + lane];
        w2r[j] = Wg[j * F_OUT + 64 + lane];
    }
    const float bga = bg[lane];
    const float bgb = bg[64 + lane];

    for (int n = wave; n < N_NODES; n += nwav) {
        float* row = out + (long long)n * F_OUT;
        const float a = row[64 + lane];
        float y1 = bga, y2 = bgb;
        #pragma unroll
        for (int j = 0; j < HID; ++j) {
            const float aj = __shfl(a, j, 64);
            y1 = fmaf(aj, w1r[j], y1);
            y2 = fmaf(aj, w2r[j], y2);
        }
        row[lane]      = y1;
        row[64 + lane] = y2;
    }
}

extern "C" void kernel_launch(void* const* d_in, const int* in_sizes, int n_in,
                              void* d_out, int out_size, void* d_ws, size_t ws_size,
                              hipStream_t stream) {
    const float* x   = (const float*)d_in[0];
    const float* pos = (const float*)d_in[1];
    const int*   ei  = (const int*)d_in[2];    // harness delivers integers as int32
    const float* W1  = (const float*)d_in[3];
    const float* b1  = (const float*)d_in[4];
    const float* W2  = (const float*)d_in[5];
    const float* b2  = (const float*)d_in[6];
    const float* Wg  = (const float*)d_in[7];
    const float* bg  = (const float*)d_in[8];
    float* out = (float*)d_out;

    unsigned* ws   = (unsigned*)d_ws;
    unsigned* qbf  = ws + OFF_QBF;
    unsigned* bcur = ws + OFF_BCUR;
    unsigned* ovf  = ws + OFF_OVF;
    unsigned* bkt  = ws + OFF_BKT;

    // per-(bucket,sub) capacity from available workspace (overflow correct)
    long long avail = (long long)(ws_size / 4) - OFF_BKT;
    int capx = (int)(avail / ((long long)NB * SUB));
    if (capx > CAPX_MAX) capx = CAPX_MAX;
    if (capx < 32) capx = 32;

    node_pre_kernel<<<(N_NODES + 255) / 256, 256, 0, stream>>>(x, W1, b1, qbf, bcur);
    scatter_kernel<<<(N_TOTAL + 255) / 256, 256, 0, stream>>>(ei, bcur, bkt, ovf, capx);
    gather_kernel<<<NB, 256, 0, stream>>>(
        qbf, pos, bcur, bkt, W1 + F_IN * HID, W2, b2, out, capx);
    ovf_kernel<<<32, 64, 0, stream>>>(
        qbf, pos, bcur, ovf, W1 + F_IN * HID, W2, b2, (unsigned*)out);
    out_gemm_kernel<<<512, 256, 0, stream>>>(out, Wg, bg);
}

// Round 10
// 264.472 us; speedup vs baseline: 18.8853x; 1.3102x over previous
//
#include <hip/hip_runtime.h>

#define N_NODES 50000
#define N_EDGES 1600000
#define N_TOTAL (N_EDGES + N_NODES)   // edges + self loops
#define F_IN    32
#define HID     64
#define F_OUT   128
#define G       32                    // dst nodes per gather bucket
#define NB      1563                  // ceil(N_NODES / G)
#define NBIN    196                   // coarse bins: d >> 8 (256 nodes = 8 buckets)
#define CAP1_MAX 10240                // per-bin cap (mean ~8420 + ~20 sigma)
#define OVF_CAP 16384
#define W1WIN   4096                  // pass-1 window (edges per block)

// workspace layout (u32 units), ~14.5 MB max:
//   qbf      [N_NODES*32]   packed bf16 Q rows
//   cur1     [NBIN*16]      pass-1 bin cursors (64B-padded)
//   ovfc     [16]           overflow counter (slot 0)
//   cellbase [NB]           per-bucket base index into bin1 (from pass 2)
//   cellcnt  [NB]           per-bucket count
//   ovf      [OVF_CAP]
//   bin1     [NBIN*cap1]    pass-1 coarse-binned, pass-2 bucket-sorted (in place)
#define OFF_QBF   0
#define OFF_CUR1  (N_NODES * 32)
#define OFF_OVFC  (OFF_CUR1 + NBIN * 16)
#define OFF_CELLB (OFF_OVFC + 16)
#define OFF_CELLC (OFF_CELLB + NB)
#define OFF_OVF   (OFF_CELLC + NB + 2)
#define OFF_BIN   (OFF_OVF + OVF_CAP)
#define NCLR      (NBIN * 16 + 16)    // words to zero (cur1 + ovfc)

typedef __attribute__((ext_vector_type(8))) short short8;  // 8 bf16 (4 VGPRs)
typedef __attribute__((ext_vector_type(4))) float v4f;

__device__ __forceinline__ unsigned f2bf2(float a, float b) {   // pack 2 bf16 (RNE)
    unsigned ua = __float_as_uint(a), ub = __float_as_uint(b);
    ua = (ua + 0x7FFFu + ((ua >> 16) & 1u)) >> 16;
    ub = (ub + 0x7FFFu + ((ub >> 16) & 1u)) & 0xFFFF0000u;
    return ua | ub;
}

// ---------------------------------------------------------------------------
// Kernel A: Q[n] = b1 + x_n @ W1[0:32,:], packed bf16 into ws. Zeros cursors.
// ---------------------------------------------------------------------------
__global__ __launch_bounds__(256) void node_pre_kernel(
    const float* __restrict__ x,
    const float* __restrict__ W1, const float* __restrict__ b1,
    unsigned* __restrict__ qbf, unsigned* __restrict__ clr)
{
    const int n = blockIdx.x * 256 + threadIdx.x;
    if (n < NCLR) clr[n] = 0u;
    if (n >= N_NODES) return;

    float acc[HID];
    #pragma unroll
    for (int k = 0; k < HID; ++k) acc[k] = b1[k];

    const float4* x4 = (const float4*)(x + (long long)n * F_IN);
    #pragma unroll 1
    for (int c4 = 0; c4 < F_IN / 4; ++c4) {
        const float4 v = x4[c4];
        const float mv[4] = {v.x, v.y, v.z, v.w};
        #pragma unroll
        for (int qq = 0; qq < 4; ++qq) {
            const float* w = W1 + (c4 * 4 + qq) * HID;   // wave-uniform
            #pragma unroll
            for (int k = 0; k < HID; ++k) acc[k] = fmaf(mv[qq], w[k], acc[k]);
        }
    }

    uint4* o4 = (uint4*)(qbf + (unsigned)n * 32u);
    #pragma unroll
    for (int j4 = 0; j4 < 8; ++j4)
        o4[j4] = make_uint4(f2bf2(acc[j4*8+0], acc[j4*8+1]),
                            f2bf2(acc[j4*8+2], acc[j4*8+3]),
                            f2bf2(acc[j4*8+4], acc[j4*8+5]),
                            f2bf2(acc[j4*8+6], acc[j4*8+7]));
}

// ---------------------------------------------------------------------------
// Kernel B1: pass-1 binning. Each block LDS-sorts a 4096-edge window into 196
// coarse bins and flushes each bin run with ONE global atomicAdd + coalesced
// stores. Global atomics: 403 blocks x 196 bins ~= 79K (was 1.65M; rounds 8/9
// showed total atomic count, not chain depth, is the scatter bound).
// Entry format: (d << 16) | s  (both < 65536).
// ---------------------------------------------------------------------------
__global__ __launch_bounds__(1024) void bin_kernel(
    const int* __restrict__ ei, unsigned* __restrict__ cur1,
    unsigned* __restrict__ bin1, unsigned* __restrict__ ovfc,
    unsigned* __restrict__ ovf, int cap1)
{
    __shared__ unsigned stage[W1WIN];       // 16 KB
    __shared__ unsigned binid[W1WIN];       // 16 KB
    __shared__ unsigned hist[NBIN], startp[NBIN + 1], gbase[NBIN];

    const int t = threadIdx.x;
    const int wbase = blockIdx.x * W1WIN;

    for (int i = t; i < NBIN; i += 1024) hist[i] = 0u;
    __syncthreads();

    unsigned ev[4]; int bv[4]; unsigned rv[4]; bool val[4];
    #pragma unroll
    for (int k = 0; k < 4; ++k) {
        const int idx = wbase + k * 1024 + t;
        val[k] = idx < N_TOTAL;
        if (val[k]) {
            int s, d;
            if (idx < N_EDGES) { s = ei[idx]; d = ei[N_EDGES + idx]; }
            else               { s = d = idx - N_EDGES; }    // self loop
            ev[k] = ((unsigned)d << 16) | (unsigned)s;
            bv[k] = d >> 8;
            rv[k] = atomicAdd(&hist[bv[k]], 1u);
        }
    }
    __syncthreads();

    if (t == 0) {
        unsigned run = 0;
        #pragma unroll 1
        for (int b = 0; b < NBIN; ++b) { startp[b] = run; run += hist[b]; }
        startp[NBIN] = run;
    }
    __syncthreads();
    if (t < NBIN && hist[t]) gbase[t] = atomicAdd(&cur1[t * 16], hist[t]);

    #pragma unroll
    for (int k = 0; k < 4; ++k)
        if (val[k]) {
            const unsigned pos = startp[bv[k]] + rv[k];
            stage[pos] = ev[k]; binid[pos] = (unsigned)bv[k];
        }
    __syncthreads();

    const unsigned total = startp[NBIN];
    for (unsigned i = t; i < total; i += 1024u) {
        const unsigned b = binid[i];
        const unsigned gp = gbase[b] + (i - startp[b]);
        if (gp < (unsigned)cap1) bin1[b * (unsigned)cap1 + gp] = stage[i];
        else {
            const unsigned qo = atomicAdd(ovfc, 1u);
            if (qo < OVF_CAP) ovf[qo] = stage[i];
        }
    }
}

// ---------------------------------------------------------------------------
// Kernel B2: pass-2 refine. One block per bin: load the whole bin into LDS,
// count its 8 gather-buckets (32-way replicated LDS counters: 2-way collisions
// only), prefix, rewrite IN PLACE bucket-sorted. Zero global atomics.
// Emits cellbase/cellcnt per bucket. Output entry: (dloc5 << 16) | s.
// ---------------------------------------------------------------------------
__global__ __launch_bounds__(1024) void refine_kernel(
    unsigned* __restrict__ bin1, const unsigned* __restrict__ cur1,
    unsigned* __restrict__ cellbase, unsigned* __restrict__ cellcnt, int cap1)
{
    __shared__ unsigned ebuf[CAP1_MAX];     // 40 KB
    __shared__ unsigned cnt32[8 * 32];      // [fb][rep], bank = rep
    __shared__ unsigned startp[8];

    const int bb = blockIdx.x, t = threadIdx.x;
    const unsigned n1 = min(cur1[bb * 16], (unsigned)cap1);
    const unsigned base1 = (unsigned)bb * (unsigned)cap1;
    const int rep = t & 31;

    for (int i = t; i < 8 * 32; i += 1024) cnt32[i] = 0u;
    __syncthreads();

    for (unsigned i = t; i < n1; i += 1024u) {
        const unsigned e = bin1[base1 + i];
        ebuf[i] = e;
        const int fb = (int)((e >> 21) & 7u);   // (d & 255) >> 5
        atomicAdd(&cnt32[fb * 32 + rep], 1u);
    }
    __syncthreads();

    if (t == 0) {
        unsigned run = 0;
        #pragma unroll
        for (int fb = 0; fb < 8; ++fb) {
            startp[fb] = run;
            unsigned s2 = run;
            #pragma unroll
            for (int r = 0; r < 32; ++r) {      // cnt32 becomes write cursors
                const unsigned c = cnt32[fb * 32 + r];
                cnt32[fb * 32 + r] = s2; s2 += c;
            }
            run = s2;
        }
    }
    __syncthreads();

    if (t < 8) {
        const int cell = bb * 8 + t;
        if (cell < NB) {
            cellbase[cell] = base1 + startp[t];
            cellcnt[cell]  = ((t < 7) ? startp[t + 1] : n1) - startp[t];
        }
    }

    for (unsigned i = t; i < n1; i += 1024u) {
        const unsigned e = ebuf[i];
        const int fb = (int)((e >> 21) & 7u);
        const unsigned p = atomicAdd(&cnt32[fb * 32 + rep], 1u);
        bin1[base1 + p] = (((e >> 16) & 31u) << 16) | (e & 0xFFFFu);
    }
}

// ---------------------------------------------------------------------------
// Kernel C: gather — one block (4 waves) per bucket, reading its contiguous
// run [cellbase, cellbase+cellcnt). layer1 fp32 (bf16 Q gather + pos part) ->
// bf16 A-frags in per-wave LDS -> 32x mfma_f32_16x16x32_bf16 -> +b2/relu ->
// block-owned LDS atomicMax -> plain coalesced store. All cross-lane LDS
// handoffs fenced with __syncthreads (round-7 lesson).
// ---------------------------------------------------------------------------
__global__ __launch_bounds__(256, 4) void gather_kernel(
    const unsigned* __restrict__ qbf,   // [N,32] packed bf16 Q
    const float* __restrict__ pos,
    const unsigned* __restrict__ cellbase,
    const unsigned* __restrict__ cellcnt,
    const unsigned* __restrict__ bkt,
    const float* __restrict__ W1p,      // W1 rows 32..34, [3, 64]
    const float* __restrict__ W2, const float* __restrict__ b2,
    float* __restrict__ out)
{
    __shared__ unsigned aggs[G * HID];      // 8 KB block-owned agg
    __shared__ unsigned w2t[64 * 36];       // 9 KB: W2^T bf16, row n, stride 36 u32
    __shared__ unsigned ast[4][64 * 20];    // 20 KB: per-wave A-stage (k-half)
    __shared__ int      wdl[4][64];         // 1 KB: per-wave dst-locals
    __shared__ float    posd[G * 3];        // bucket nodes' pos

    const int t = threadIdx.x, lane = t & 63, w = t >> 6;
    const int q = lane >> 4, m15 = lane & 15;
    const int b = blockIdx.x;
    const unsigned cnt  = cellcnt[b];
    const unsigned base = cellbase[b];

    for (int i = t; i < G * HID; i += 256) aggs[i] = 0u;
    for (int i = t; i < 64 * 32; i += 256) {            // W2^T -> bf16 LDS
        const int n = i >> 5, ku = i & 31;              // k-pair index
        w2t[n * 36 + ku] = f2bf2(W2[(2 * ku) * HID + n], W2[(2 * ku + 1) * HID + n]);
    }
    for (int i = t; i < G * 3; i += 256) {
        const int node = b * G + i / 3;
        posd[i] = (node < N_NODES) ? pos[node * 3 + i % 3] : 0.f;
    }
    __syncthreads();

    float b2v[4];
    #pragma unroll
    for (int nt = 0; nt < 4; ++nt) b2v[nt] = b2[nt * 16 + m15];

    unsigned* aw = ast[w];
    int* wd = wdl[w];
    const unsigned nit = (cnt + 255u) >> 8;     // block-uniform iteration count

    #pragma unroll 1
    for (unsigned it = 0; it < nit; ++it) {
        const unsigned off = it * 256u + (unsigned)w * 64u;
        const unsigned rem = (off < cnt) ? min(64u, cnt - off) : 0u;
        const unsigned f = off + (unsigned)lane;
        int s = 0, dl = 0;
        if (f < cnt) {
            const unsigned p = bkt[base + f];
            s = (int)(p & 0xFFFFu); dl = (int)(p >> 16);
        }
        wd[lane] = dl;

        // Q row: 8 x b128 issued up front (outstanding during layer-1 compute)
        const uint4* qr = (const uint4*)(qbf + (unsigned)s * 32u);
        uint4 qv[8];
        #pragma unroll
        for (int i = 0; i < 8; ++i) qv[i] = qr[i];

        const float pd0 = pos[s * 3 + 0] - posd[dl * 3 + 0];
        const float pd1 = pos[s * 3 + 1] - posd[dl * 3 + 1];
        const float pd2 = pos[s * 3 + 2] - posd[dl * 3 + 2];

        short8 a0[4], a1[4];
        #pragma unroll
        for (int hf = 0; hf < 2; ++hf) {
            const int c0 = hf * 32;
            float hc[32];
            #pragma unroll
            for (int j4 = 0; j4 < 4; ++j4) {
                const uint4 v = qv[hf * 4 + j4];
                const unsigned uu[4] = {v.x, v.y, v.z, v.w};
                #pragma unroll
                for (int p2 = 0; p2 < 4; ++p2) {
                    hc[j4 * 8 + p2 * 2    ] = __uint_as_float(uu[p2] << 16);
                    hc[j4 * 8 + p2 * 2 + 1] = __uint_as_float(uu[p2] & 0xFFFF0000u);
                }
            }
            #pragma unroll
            for (int k = 0; k < 32; ++k) {
                float v = hc[k];
                v = fmaf(pd0, W1p[0 * HID + c0 + k], v);    // wave-uniform
                v = fmaf(pd1, W1p[1 * HID + c0 + k], v);
                v = fmaf(pd2, W1p[2 * HID + c0 + k], v);
                hc[k] = fmaxf(v, 0.f);
            }
            // pack + stage in A-frag order: row=edge(lane), 16 u32, stride 20
            uint4* dst = (uint4*)(aw + lane * 20);
            #pragma unroll
            for (int j4 = 0; j4 < 4; ++j4)
                dst[j4] = make_uint4(f2bf2(hc[j4*8+0], hc[j4*8+1]),
                                     f2bf2(hc[j4*8+2], hc[j4*8+3]),
                                     f2bf2(hc[j4*8+4], hc[j4*8+5]),
                                     f2bf2(hc[j4*8+6], hc[j4*8+7]));
            __syncthreads();                    // stage-write -> cross-lane read
            short8* af = hf ? a1 : a0;
            #pragma unroll
            for (int mt = 0; mt < 4; ++mt)
                af[mt] = *(const short8*)(aw + (mt * 16 + m15) * 20 + q * 4);
            __syncthreads();                    // read done -> next overwrite ok
        }

        // ---- MFMA layer 2 + epilogue, in two 32-channel halves ----
        #pragma unroll
        for (int h = 0; h < 2; ++h) {
            short8 bf[2][2];    // [ntl][ks]
            #pragma unroll
            for (int ntl = 0; ntl < 2; ++ntl)
                #pragma unroll
                for (int ks = 0; ks < 2; ++ks)
                    bf[ntl][ks] = *(const short8*)(
                        w2t + ((2 * h + ntl) * 16 + m15) * 36 + ks * 16 + q * 4);
            v4f c[4][2] = {};
            #pragma unroll
            for (int mt = 0; mt < 4; ++mt)
                #pragma unroll
                for (int ntl = 0; ntl < 2; ++ntl) {
                    c[mt][ntl] = __builtin_amdgcn_mfma_f32_16x16x32_bf16(
                        a0[mt], bf[ntl][0], c[mt][ntl], 0, 0, 0);
                    c[mt][ntl] = __builtin_amdgcn_mfma_f32_16x16x32_bf16(
                        a1[mt], bf[ntl][1], c[mt][ntl], 0, 0, 0);
                }
            #pragma unroll
            for (int mt = 0; mt < 4; ++mt) {
                #pragma unroll
                for (int r = 0; r < 4; ++r) {
                    const int er = mt * 16 + q * 4 + r;   // edge index in batch
                    const int dle = wd[er];
                    const bool vv = (unsigned)er < rem;
                    #pragma unroll
                    for (int ntl = 0; ntl < 2; ++ntl) {
                        const int nt = 2 * h + ntl;
                        const float hv = fmaxf(c[mt][ntl][r] + b2v[nt], 0.f);
                        if (vv)
                            atomicMax(&aggs[dle * HID + nt * 16 + m15],
                                      __float_as_uint(hv));
                    }
                }
            }
        }
        __syncthreads();    // epilogue wd/agg reads done -> next wd write ok
    }
    __syncthreads();

    for (int i = t; i < G * HID; i += 256) {
        const int row = i >> 6, ch = i & 63, n = b * G + row;
        if (n < N_NODES)
            out[(long long)n * F_OUT + HID + ch] = __uint_as_float(aggs[i]);
    }
}

// ---------------------------------------------------------------------------
// Kernel D: overflow fixup (~0 edges in practice; correct for any count).
// Numerics match the MFMA path (h1 and W2 rounded to bf16). Entry: (d<<16)|s.
// ---------------------------------------------------------------------------
__global__ __launch_bounds__(64) void ovf_kernel(
    const unsigned* __restrict__ qbf, const float* __restrict__ pos,
    const unsigned* __restrict__ ovfc, const unsigned* __restrict__ ovf,
    const float* __restrict__ W1p, const float* __restrict__ W2,
    const float* __restrict__ b2, unsigned* __restrict__ aggbits)
{
    const unsigned n = min(*ovfc, (unsigned)OVF_CAP);
    for (unsigned i = blockIdx.x * 64 + threadIdx.x; i < n; i += gridDim.x * 64) {
        const unsigned p = ovf[i];
        const int s = (int)(p & 0xFFFFu), d = (int)(p >> 16);
        float h1[HID];
        #pragma unroll 1
        for (int k = 0; k < HID; ++k) {
            const unsigned u = qbf[s * 32 + (k >> 1)];
            h1[k] = (k & 1) ? __uint_as_float(u & 0xFFFF0000u)
                            : __uint_as_float(u << 16);
        }
        #pragma unroll 1
        for (int a = 0; a < 3; ++a) {
            const float pd = pos[s * 3 + a] - pos[d * 3 + a];
            #pragma unroll 1
            for (int k = 0; k < HID; ++k) h1[k] = fmaf(pd, W1p[a * HID + k], h1[k]);
        }
        #pragma unroll 1
        for (int k = 0; k < HID; ++k) {
            const unsigned hb = f2bf2(fmaxf(h1[k], 0.f), 0.f) << 16;
            h1[k] = __uint_as_float(hb);
        }
        unsigned* ap = aggbits + (long long)d * F_OUT + HID;
        #pragma unroll 1
        for (int k = 0; k < HID; ++k) {
            float a2 = b2[k];
            #pragma unroll 1
            for (int j = 0; j < HID; ++j) {
                const float w2b = __uint_as_float(f2bf2(W2[j * HID + k], 0.f) << 16);
                a2 = fmaf(h1[j], w2b, a2);
            }
            a2 = fmaxf(a2, 0.f);
            atomicMax(ap + k, __float_as_uint(a2));
        }
    }
}

// ---------------------------------------------------------------------------
// Kernel E: out[n] = agg[n] @ Wg + bg, in place (wave per node, Wg columns in
// registers, agg broadcast via shfl; wave-internal read->write is race-free).
// ---------------------------------------------------------------------------
__global__ __launch_bounds__(256) void out_gemm_kernel(
    float* __restrict__ out,            // [N_NODES, 128]
    const float* __restrict__ Wg,       // [HID, F_OUT]
    const float* __restrict__ bg)       // [F_OUT]
{
    const int lane = threadIdx.x & 63;
    const int wave = blockIdx.x * (blockDim.x >> 6) + (threadIdx.x >> 6);
    const int nwav = gridDim.x * (blockDim.x >> 6);

    float w1r[HID], w2r[HID];
    #pragma unroll
    for (int j = 0; j < HID; ++j) {
        w1r[j] = Wg[j * F_OUT + lane];
        w2r[j] = Wg[j * F_OUT + 64 + lane];
    }
    const float bga = bg[lane];
    const float bgb = bg[64 + lane];

    for (int n = wave; n < N_NODES; n += nwav) {
        float* row = out + (long long)n * F_OUT;
        const float a = row[64 + lane];
        float y1 = bga, y2 = bgb;
        #pragma unroll
        for (int j = 0; j < HID; ++j) {
            const float aj = __shfl(a, j, 64);
            y1 = fmaf(aj, w1r[j], y1);
            y2 = fmaf(aj, w2r[j], y2);
        }
        row[lane]      = y1;
        row[64 + lane] = y2;
    }
}

extern "C" void kernel_launch(void* const* d_in, const int* in_sizes, int n_in,
                              void* d_out, int out_size, void* d_ws, size_t ws_size,
                              hipStream_t stream) {
    const float* x   = (const float*)d_in[0];
    const float* pos = (const float*)d_in[1];
    const int*   ei  = (const int*)d_in[2];    // harness delivers integers as int32
    const float* W1  = (const float*)d_in[3];
    const float* b1  = (const float*)d_in[4];
    const float* W2  = (const float*)d_in[5];
    const float* b2  = (const float*)d_in[6];
    const float* Wg  = (const float*)d_in[7];
    const float* bg  = (const float*)d_in[8];
    float* out = (float*)d_out;

    unsigned* ws    = (unsigned*)d_ws;
    unsigned* qbf   = ws + OFF_QBF;
    unsigned* cur1  = ws + OFF_CUR1;
    unsigned* ovfc  = ws + OFF_OVFC;
    unsigned* cellb = ws + OFF_CELLB;
    unsigned* cellc = ws + OFF_CELLC;
    unsigned* ovf   = ws + OFF_OVF;
    unsigned* bin1  = ws + OFF_BIN;

    // per-bin capacity from available workspace (overflow path correct anyway)
    long long avail = (long long)(ws_size / 4) - OFF_BIN;
    int cap1 = (int)(avail / NBIN);
    if (cap1 > CAP1_MAX) cap1 = CAP1_MAX;
    if (cap1 < 2048) cap1 = 2048;

    node_pre_kernel<<<(N_NODES + 255) / 256, 256, 0, stream>>>(x, W1, b1, qbf, cur1);
    bin_kernel<<<(N_TOTAL + W1WIN - 1) / W1WIN, 1024, 0, stream>>>(
        ei, cur1, bin1, ovfc, ovf, cap1);
    refine_kernel<<<NBIN, 1024, 0, stream>>>(bin1, cur1, cellb, cellc, cap1);
    gather_kernel<<<NB, 256, 0, stream>>>(
        qbf, pos, cellb, cellc, bin1, W1 + F_IN * HID, W2, b2, out);
    ovf_kernel<<<32, 64, 0, stream>>>(
        qbf, pos, ovfc, ovf, W1 + F_IN * HID, W2, b2, (unsigned*)out);
    out_gemm_kernel<<<512, 256, 0, stream>>>(out, Wg, bg);
}